// Round 1
// baseline (146.526 us; speedup 1.0000x reference)
//
#include <hip/hip_runtime.h>

#define B_N 4096
#define M_N 3
#define D_N 256
#define LOG2E 1.44269504088896340736f
#define LN2   0.69314718055994530942f

typedef __bf16 bf16x8 __attribute__((ext_vector_type(8)));
typedef float  f32x4  __attribute__((ext_vector_type(4)));

__device__ __forceinline__ unsigned short f2bf(float f) {
    unsigned int u = __float_as_uint(f);
    u += 0x7FFFu + ((u >> 16) & 1u);   // round-to-nearest-even
    return (unsigned short)(u >> 16);
}

// tokens [i][m][d] fp32 -> tokb [m][i][d] bf16
__global__ void cvt_kernel(const float* __restrict__ in, unsigned short* __restrict__ out) {
    int idx = blockIdx.x * blockDim.x + threadIdx.x;   // < B*M*D/4 = 786432
    if (idx >= (B_N * M_N * D_N) / 4) return;
    float4 v = reinterpret_cast<const float4*>(in)[idx];
    int i   = idx / 192;           // 192 = M*D/4
    int rem = idx - i * 192;
    int m   = rem >> 6;            // D/4 = 64
    int d4  = rem & 63;
    ushort4 o;
    o.x = f2bf(v.x); o.y = f2bf(v.y); o.z = f2bf(v.z); o.w = f2bf(v.w);
    reinterpret_cast<ushort4*>(out)[((size_t)m * B_N + i) * 64 + d4] = o;
}

// label histogram (32 classes) + count of valid samples
__global__ void hist_kernel(const int* __restrict__ labels, int* __restrict__ hist,
                            int* __restrict__ nvout) {
    __shared__ int h[32];
    __shared__ int nv;
    int tid = threadIdx.x;
    if (tid < 32) h[tid] = 0;
    if (tid == 0) nv = 0;
    __syncthreads();
    for (int i = tid; i < B_N; i += 256) atomicAdd(&h[labels[i]], 1);
    __syncthreads();
    int cnt = 0;
    for (int i = tid; i < B_N; i += 256) cnt += (h[labels[i]] >= 2) ? 1 : 0;
    atomicAdd(&nv, cnt);
    __syncthreads();
    if (tid < 32) hist[tid] = h[tid];
    if (tid == 0) nvout[0] = nv;
}

// Fused sim-GEMM + online LSE + positive-sum.
// grid = 3 * 128 blocks; block = 256 threads (4 waves).
// Block handles rows [i0, i0+32) of modality m; wave w handles cols [w*1024,(w+1)*1024).
__global__ __launch_bounds__(256) void main_kernel(
    const unsigned short* __restrict__ tokb, const int* __restrict__ labels,
    const int* __restrict__ hist, float* __restrict__ partials) {
    int bid = blockIdx.x;
    int m   = bid >> 7;           // 128 row-blocks per modality
    int rb  = bid & 127;
    int i0  = rb * 32;
    int tid  = threadIdx.x;
    int wave = tid >> 6, lane = tid & 63;
    int lr = lane & 15;           // row (A) / col (B) index within 16-tile
    int lk = lane >> 4;           // k-group
    const unsigned short* tm = tokb + (size_t)m * B_N * D_N;

    // A fragments: rows i0 + rt*16 + lr, held in registers for the whole kernel
    bf16x8 afrag[2][8];
#pragma unroll
    for (int rt = 0; rt < 2; ++rt) {
        const unsigned short* rp = tm + (size_t)(i0 + rt * 16 + lr) * D_N + lk * 8;
#pragma unroll
        for (int kf = 0; kf < 8; ++kf)
            afrag[rt][kf] = *reinterpret_cast<const bf16x8*>(rp + kf * 32);
    }

    // labels of the rows this lane accumulates (C/D layout: row=(lane>>4)*4+j)
    int labr[2][4], rowg[2][4];
#pragma unroll
    for (int rt = 0; rt < 2; ++rt)
#pragma unroll
        for (int j = 0; j < 4; ++j) {
            rowg[rt][j] = i0 + rt * 16 + lk * 4 + j;
            labr[rt][j] = labels[rowg[rt][j]];
        }

    float rM[2][4], rS[2][4], rP[2][4];
#pragma unroll
    for (int rt = 0; rt < 2; ++rt)
#pragma unroll
        for (int j = 0; j < 4; ++j) { rM[rt][j] = -3e38f; rS[rt][j] = 0.f; rP[rt][j] = 0.f; }

    int wbase = wave * 1024;
    for (int kb = 0; kb < 64; ++kb) {
        int colg = wbase + kb * 16 + lr;
        int labc = labels[colg];
        const unsigned short* cp = tm + (size_t)colg * D_N + lk * 8;
        bf16x8 bfrag[8];
#pragma unroll
        for (int kf = 0; kf < 8; ++kf)
            bfrag[kf] = *reinterpret_cast<const bf16x8*>(cp + kf * 32);
        f32x4 acc0 = {0.f, 0.f, 0.f, 0.f};
        f32x4 acc1 = {0.f, 0.f, 0.f, 0.f};
#pragma unroll
        for (int kf = 0; kf < 8; ++kf) {
            acc0 = __builtin_amdgcn_mfma_f32_16x16x32_bf16(afrag[0][kf], bfrag[kf], acc0, 0, 0, 0);
            acc1 = __builtin_amdgcn_mfma_f32_16x16x32_bf16(afrag[1][kf], bfrag[kf], acc1, 0, 0, 0);
        }
#pragma unroll
        for (int rt = 0; rt < 2; ++rt) {
#pragma unroll
            for (int j = 0; j < 4; ++j) {
                float s = (rt == 0) ? acc0[j] : acc1[j];
                bool diag = (colg == rowg[rt][j]);
                bool pos  = (labc == labr[rt][j]) && !diag;
                rP[rt][j] += pos ? s : 0.f;
                float t  = s * LOG2E;
                float nm = fmaxf(rM[rt][j], t);
                float ns = rS[rt][j] * __builtin_amdgcn_exp2f(rM[rt][j] - nm)
                         + __builtin_amdgcn_exp2f(t - nm);
                rM[rt][j] = diag ? rM[rt][j] : nm;
                rS[rt][j] = diag ? rS[rt][j] : ns;
            }
        }
    }

    // merge across the 16 column-lanes (lanes sharing lk hold the same rows)
    __shared__ float sM[4][32], sS[4][32], sP[4][32];
#pragma unroll
    for (int rt = 0; rt < 2; ++rt)
#pragma unroll
        for (int j = 0; j < 4; ++j) {
            float M = rM[rt][j], S = rS[rt][j], P = rP[rt][j];
#pragma unroll
            for (int msk = 1; msk < 16; msk <<= 1) {
                float om = __shfl_xor(M, msk);
                float os = __shfl_xor(S, msk);
                float op = __shfl_xor(P, msk);
                float nm = fmaxf(M, om);
                S = S * __builtin_amdgcn_exp2f(M - nm) + os * __builtin_amdgcn_exp2f(om - nm);
                M = nm;
                P += op;
            }
            if (lr == 0) {
                int rl = rt * 16 + lk * 4 + j;
                sM[wave][rl] = M; sS[wave][rl] = S; sP[wave][rl] = P;
            }
        }
    __syncthreads();

    if (tid < 32) {
        float M = -3e38f, S = 0.f, P = 0.f;
#pragma unroll
        for (int w = 0; w < 4; ++w) {
            float m2 = sM[w][tid], s2 = sS[w][tid];
            float nm = fmaxf(M, m2);
            S = S * __builtin_amdgcn_exp2f(M - nm) + s2 * __builtin_amdgcn_exp2f(m2 - nm);
            M = nm;
            P += sP[w][tid];
        }
        float lse = (M + __builtin_amdgcn_logf(S)) * LN2;   // natural-log lse
        int lab = labels[i0 + tid];
        int pc  = hist[lab] - 1;
        float contrib = (pc > 0) ? (lse - P / (float)pc) : 0.f;  // = -per[i,m]
#pragma unroll
        for (int off = 16; off >= 1; off >>= 1)
            contrib += __shfl_down(contrib, off);
        if (tid == 0) partials[bid] = contrib;
    }
}

__global__ void final_kernel(const float* __restrict__ partials, const int* __restrict__ nv,
                             float* __restrict__ out) {
    int lane = threadIdx.x;
    float s = 0.f;
    for (int i = lane; i < 384; i += 64) s += partials[i];
#pragma unroll
    for (int off = 32; off >= 1; off >>= 1) s += __shfl_down(s, off);
    if (lane == 0) out[0] = s / (float)(nv[0] * M_N);
}

extern "C" void kernel_launch(void* const* d_in, const int* in_sizes, int n_in,
                              void* d_out, int out_size, void* d_ws, size_t ws_size,
                              hipStream_t stream) {
    const float* tokens = (const float*)d_in[0];
    const int*   labels = (const int*)d_in[1];
    float* out = (float*)d_out;

    char* ws = (char*)d_ws;
    int*   hist     = (int*)ws;                    // 32 ints
    int*   nv       = (int*)(ws + 128);            // 1 int
    float* partials = (float*)(ws + 256);          // 384 floats
    unsigned short* tokb = (unsigned short*)(ws + 2048);  // 3*4096*256 bf16 = 6.29 MB

    cvt_kernel<<<3072, 256, 0, stream>>>(tokens, tokb);
    hist_kernel<<<1, 256, 0, stream>>>(labels, hist, nv);
    main_kernel<<<384, 256, 0, stream>>>(tokb, labels, hist, partials);
    final_kernel<<<1, 64, 0, stream>>>(partials, nv, out);
}